// Round 1
// baseline (1276.935 us; speedup 1.0000x reference)
//
#include <hip/hip_runtime.h>

#define Bb 2
#define Hh 16
#define Ss 2048
#define Dd 128

typedef _Float16 half_t;
typedef __attribute__((ext_vector_type(4))) float floatx4;
typedef __attribute__((ext_vector_type(8))) _Float16 halfx8;
typedef __attribute__((ext_vector_type(4))) _Float16 halfx4;

// ---- V transpose+cast: [B*H, S, D] f32 -> [B*H, D, S] f16 (into d_ws) ----
__global__ __launch_bounds__(256) void vt_kernel(const float* __restrict__ V,
                                                 half_t* __restrict__ Vt) {
  __shared__ __align__(16) half_t t[64 * 72];  // [d][k], stride 72 (144B = 16*9)
  const int bh = blockIdx.z;
  const int k0 = blockIdx.x * 64;
  const int d0 = blockIdx.y * 64;
  const int tid = threadIdx.x;
  const float* src = V + ((size_t)bh * Ss + k0) * Dd + d0;
  for (int idx = tid; idx < 64 * 16; idx += 256) {
    int r = idx >> 4;           // key row
    int c4 = (idx & 15) << 2;   // d offset
    floatx4 v = *(const floatx4*)(src + (size_t)r * Dd + c4);
    t[(c4 + 0) * 72 + r] = (half_t)v.x;
    t[(c4 + 1) * 72 + r] = (half_t)v.y;
    t[(c4 + 2) * 72 + r] = (half_t)v.z;
    t[(c4 + 3) * 72 + r] = (half_t)v.w;
  }
  __syncthreads();
  half_t* dst = Vt + ((size_t)bh * Dd + d0) * Ss + k0;
  for (int idx = tid; idx < 64 * 8; idx += 256) {
    int r = idx >> 3;           // d row
    int c8 = (idx & 7) << 3;    // key offset
    *(halfx8*)(dst + (size_t)r * Ss + c8) = *(const halfx8*)&t[r * 72 + c8];
  }
}

// ---- fused attention: QK^T (MFMA f16) -> softmax (2-pass, no max) -> PV ----
__global__ __launch_bounds__(256) void attn_kernel(
    const float* __restrict__ Q, const float* __restrict__ K,
    const int* __restrict__ mask, const float* __restrict__ scale_p,
    const half_t* __restrict__ Vt, float* __restrict__ ctx_out,
    float* __restrict__ attn_out) {
  __shared__ __align__(16) half_t Qs[64 * 136];   // stride 136 (272B = 16*17)
  __shared__ __align__(16) half_t Ks[64 * 136];
  __shared__ __align__(16) half_t Vts[128 * 72];  // [d][k]
  __shared__ __align__(16) half_t Ps[4 * 16 * 72]; // per-wave 16x64 P tile

  const int tid = threadIdx.x;
  const int wave = tid >> 6;
  const int lane = tid & 63;
  const int quad = lane >> 4;
  const int l16 = lane & 15;
  const int q0 = blockIdx.x * 64;
  const int h = blockIdx.y;
  const int b = blockIdx.z;
  const int bh = b * Hh + h;
  const float scale = scale_p[0];

  const float* Qg = Q + ((size_t)bh * Ss + q0) * Dd;
  const float* Kg = K + (size_t)bh * Ss * Dd;
  const half_t* Vtg = Vt + (size_t)bh * Dd * Ss;
  const int* Mg = mask + (size_t)b * Ss * Ss;

  // stage Q tile (64 x 128) fp32 -> fp16 LDS
  for (int idx = tid; idx < 64 * 32; idx += 256) {
    int r = idx >> 5, c4 = (idx & 31) << 2;
    floatx4 v = *(const floatx4*)(Qg + (size_t)r * Dd + c4);
    halfx4 hv = {(half_t)v.x, (half_t)v.y, (half_t)v.z, (half_t)v.w};
    *(halfx4*)&Qs[r * 136 + c4] = hv;
  }

  const int arow = 16 * wave + l16;          // A-frag row (local q)
  const int qrow = q0 + 16 * wave + quad * 4; // C-layout row base (global q)

  float lacc[4] = {0.f, 0.f, 0.f, 0.f};

  // ---------------- pass 1: row sums of exp(masked scaled scores) ----------
  for (int kt = 0; kt < Ss / 64; ++kt) {
    const int k0 = kt * 64;
    __syncthreads();
    for (int idx = tid; idx < 64 * 32; idx += 256) {
      int r = idx >> 5, c4 = (idx & 31) << 2;
      floatx4 v = *(const floatx4*)(Kg + (size_t)(k0 + r) * Dd + c4);
      halfx4 hv = {(half_t)v.x, (half_t)v.y, (half_t)v.z, (half_t)v.w};
      *(halfx4*)&Ks[r * 136 + c4] = hv;
    }
    __syncthreads();
#pragma unroll
    for (int nt = 0; nt < 4; ++nt) {
      floatx4 acc = {0.f, 0.f, 0.f, 0.f};
#pragma unroll
      for (int ks = 0; ks < 4; ++ks) {
        halfx8 a = *(const halfx8*)&Qs[arow * 136 + ks * 32 + quad * 8];
        halfx8 bf = *(const halfx8*)&Ks[(nt * 16 + l16) * 136 + ks * 32 + quad * 8];
        acc = __builtin_amdgcn_mfma_f32_16x16x32_f16(a, bf, acc, 0, 0, 0);
      }
      const int kcol = k0 + nt * 16 + l16;
#pragma unroll
      for (int r = 0; r < 4; ++r) {
        int q = qrow + r;
        int m = Mg[(size_t)q * Ss + kcol];
        float e = m ? __expf(acc[r] * scale) : 0.0f;
        e += __shfl_xor(e, 1);
        e += __shfl_xor(e, 2);
        e += __shfl_xor(e, 4);
        e += __shfl_xor(e, 8);
        lacc[r] += e;  // row sum over this 16-col group, all quad lanes hold it
      }
    }
  }
  float inv[4];
#pragma unroll
  for (int r = 0; r < 4; ++r) inv[r] = 1.0f / lacc[r];

  floatx4 cacc[8];
#pragma unroll
  for (int i = 0; i < 8; ++i) cacc[i] = (floatx4){0.f, 0.f, 0.f, 0.f};

  float* attn_base = attn_out + (size_t)bh * Ss * Ss;

  // ---------------- pass 2: write normalized attention + fused PV ----------
  for (int kt = 0; kt < Ss / 64; ++kt) {
    const int k0 = kt * 64;
    __syncthreads();
    for (int idx = tid; idx < 64 * 32; idx += 256) {
      int r = idx >> 5, c4 = (idx & 31) << 2;
      floatx4 v = *(const floatx4*)(Kg + (size_t)(k0 + r) * Dd + c4);
      halfx4 hv = {(half_t)v.x, (half_t)v.y, (half_t)v.z, (half_t)v.w};
      *(halfx4*)&Ks[r * 136 + c4] = hv;
    }
    for (int idx = tid; idx < 128 * 8; idx += 256) {
      int r = idx >> 3, c8 = (idx & 7) << 3;
      *(halfx8*)&Vts[r * 72 + c8] =
          *(const halfx8*)(Vtg + (size_t)r * Ss + k0 + c8);
    }
    __syncthreads();
#pragma unroll
    for (int nt = 0; nt < 4; ++nt) {
      floatx4 acc = {0.f, 0.f, 0.f, 0.f};
#pragma unroll
      for (int ks = 0; ks < 4; ++ks) {
        halfx8 a = *(const halfx8*)&Qs[arow * 136 + ks * 32 + quad * 8];
        halfx8 bf = *(const halfx8*)&Ks[(nt * 16 + l16) * 136 + ks * 32 + quad * 8];
        acc = __builtin_amdgcn_mfma_f32_16x16x32_f16(a, bf, acc, 0, 0, 0);
      }
      const int kcol = k0 + nt * 16 + l16;
#pragma unroll
      for (int r = 0; r < 4; ++r) {
        int q = qrow + r;
        int m = Mg[(size_t)q * Ss + kcol];
        float p = m ? __expf(acc[r] * scale) * inv[r] : 0.0f;
        attn_base[(size_t)q * Ss + kcol] = p;
        Ps[wave * (16 * 72) + (quad * 4 + r) * 72 + nt * 16 + l16] = (half_t)p;
      }
    }
    // PV: context[q, d] += P[q, k] * V[k, d]; A = Ps (own wave's rows), B = Vts
#pragma unroll
    for (int nt2 = 0; nt2 < 8; ++nt2) {
#pragma unroll
      for (int ks = 0; ks < 2; ++ks) {
        halfx8 a = *(const halfx8*)&Ps[wave * (16 * 72) + l16 * 72 + ks * 32 + quad * 8];
        halfx8 bv = *(const halfx8*)&Vts[(nt2 * 16 + l16) * 72 + ks * 32 + quad * 8];
        cacc[nt2] = __builtin_amdgcn_mfma_f32_16x16x32_f16(a, bv, cacc[nt2], 0, 0, 0);
      }
    }
  }

  // epilogue: write context
  float* ctx = ctx_out + (size_t)bh * Ss * Dd;
#pragma unroll
  for (int nt2 = 0; nt2 < 8; ++nt2) {
#pragma unroll
    for (int r = 0; r < 4; ++r) {
      ctx[(size_t)(qrow + r) * Dd + nt2 * 16 + l16] = cacc[nt2][r];
    }
  }
}

extern "C" void kernel_launch(void* const* d_in, const int* in_sizes, int n_in,
                              void* d_out, int out_size, void* d_ws, size_t ws_size,
                              hipStream_t stream) {
  const float* Q = (const float*)d_in[0];
  const float* K = (const float*)d_in[1];
  const float* V = (const float*)d_in[2];
  const int* mask = (const int*)d_in[3];
  const float* scale = (const float*)d_in[4];
  float* ctx = (float*)d_out;                                  // [B,H,S,D]
  float* attn = (float*)d_out + (size_t)Bb * Hh * Ss * Dd;     // [B,H,S,S]
  half_t* Vt = (half_t*)d_ws;                                  // [B,H,D,S] f16

  dim3 gt(Ss / 64, Dd / 64, Bb * Hh);
  vt_kernel<<<gt, 256, 0, stream>>>(V, Vt);
  dim3 gm(Ss / 64, Hh, Bb);
  attn_kernel<<<gm, 256, 0, stream>>>(Q, K, mask, scale, Vt, ctx, attn);
}

// Round 2
// 952.754 us; speedup vs baseline: 1.3403x; 1.3403x over previous
//
#include <hip/hip_runtime.h>

#define Bb 2
#define Hh 16
#define Ss 2048
#define Dd 128
#define NWrd (Ss / 64)

typedef _Float16 half_t;
typedef __attribute__((ext_vector_type(4))) float floatx4;
typedef __attribute__((ext_vector_type(8))) _Float16 halfx8;
typedef unsigned long long u64;

// ---- cast Q (scale folded) and K to f16 ----
__global__ __launch_bounds__(256) void cvt_qk_kernel(
    const float* __restrict__ Q, const float* __restrict__ K,
    const float* __restrict__ scale_p,
    half_t* __restrict__ Qh, half_t* __restrict__ Kh) {
  const float s = scale_p[0];
  size_t i = ((size_t)blockIdx.x * 256 + threadIdx.x) * 8;
  floatx4 a0 = *(const floatx4*)(Q + i);
  floatx4 a1 = *(const floatx4*)(Q + i + 4);
  halfx8 hq = {(half_t)(a0.x * s), (half_t)(a0.y * s), (half_t)(a0.z * s),
               (half_t)(a0.w * s), (half_t)(a1.x * s), (half_t)(a1.y * s),
               (half_t)(a1.z * s), (half_t)(a1.w * s)};
  *(halfx8*)(Qh + i) = hq;
  floatx4 b0 = *(const floatx4*)(K + i);
  floatx4 b1 = *(const floatx4*)(K + i + 4);
  halfx8 hk = {(half_t)b0.x, (half_t)b0.y, (half_t)b0.z, (half_t)b0.w,
               (half_t)b1.x, (half_t)b1.y, (half_t)b1.z, (half_t)b1.w};
  *(halfx8*)(Kh + i) = hk;
}

// ---- V transpose+cast: [B*H, S, D] f32 -> [B*H, D, S] f16 ----
__global__ __launch_bounds__(256) void vt_kernel(const float* __restrict__ V,
                                                 half_t* __restrict__ Vt) {
  __shared__ __align__(16) half_t t[64 * 72];
  const int bh = blockIdx.z;
  const int k0 = blockIdx.x * 64;
  const int d0 = blockIdx.y * 64;
  const int tid = threadIdx.x;
  const float* src = V + ((size_t)bh * Ss + k0) * Dd + d0;
  for (int idx = tid; idx < 64 * 16; idx += 256) {
    int r = idx >> 4;
    int c4 = (idx & 15) << 2;
    floatx4 v = *(const floatx4*)(src + (size_t)r * Dd + c4);
    t[(c4 + 0) * 72 + r] = (half_t)v.x;
    t[(c4 + 1) * 72 + r] = (half_t)v.y;
    t[(c4 + 2) * 72 + r] = (half_t)v.z;
    t[(c4 + 3) * 72 + r] = (half_t)v.w;
  }
  __syncthreads();
  half_t* dst = Vt + ((size_t)bh * Dd + d0) * Ss + k0;
  for (int idx = tid; idx < 64 * 8; idx += 256) {
    int r = idx >> 3;
    int c8 = (idx & 7) << 3;
    *(halfx8*)(dst + (size_t)r * Ss + c8) = *(const halfx8*)&t[r * 72 + c8];
  }
}

// ---- pack mask ints -> bit words (one wave per 64 columns) ----
__global__ __launch_bounds__(256) void mask_pack_kernel(
    const int* __restrict__ mask, u64* __restrict__ mb) {
  size_t w = (size_t)blockIdx.x * 4 + (threadIdx.x >> 6);
  int lane = threadIdx.x & 63;
  int m = mask[w * 64 + lane];
  u64 bal = __ballot(m != 0);
  if (lane == 0) mb[w] = bal;
}

// ---- fused attention ----
__global__ __launch_bounds__(256) void attn_kernel(
    const half_t* __restrict__ Qh, const half_t* __restrict__ Kh,
    const u64* __restrict__ Mb, const half_t* __restrict__ Vt,
    float* __restrict__ ctx_out, float* __restrict__ attn_out) {
  __shared__ __align__(16) half_t Ks[64 * 136];   // 272B stride: 2-way (free)
  __shared__ __align__(16) half_t Vts[128 * 72];  // [d][k], 144B stride: 2-way
  __shared__ __align__(16) half_t Ps[4 * 16 * 72];

  const int tid = threadIdx.x;
  const int wave = tid >> 6;
  const int lane = tid & 63;
  const int quad = lane >> 4;
  const int l16 = lane & 15;
  const int q0 = blockIdx.x * 64;
  const int bh = blockIdx.z * Hh + blockIdx.y;

  const half_t* Qg = Qh + ((size_t)bh * Ss + q0) * Dd;
  const half_t* Kg = Kh + (size_t)bh * Ss * Dd;
  const half_t* Vtg = Vt + (size_t)bh * Dd * Ss;
  const u64* Mg = Mb + ((size_t)blockIdx.z * Ss + q0) * NWrd;

  // stage Q tile into Ks (temp), pull A-frags to registers, never touch again
  for (int it = 0; it < 4; ++it) {
    int idx = tid + it * 256;
    int r = idx >> 4, c8 = (idx & 15) << 3;
    *(halfx8*)&Ks[r * 136 + c8] = *(const halfx8*)(Qg + (size_t)r * Dd + c8);
  }
  __syncthreads();
  const int arow = 16 * wave + l16;
  halfx8 qa[4];
#pragma unroll
  for (int ks = 0; ks < 4; ++ks)
    qa[ks] = *(const halfx8*)&Ks[arow * 136 + ks * 32 + quad * 8];

  const int lrow = 16 * wave + quad * 4;  // local C-layout row base
  const int qrow = q0 + lrow;             // global (within head)
  float lacc[4] = {0.f, 0.f, 0.f, 0.f};

  // -------- pass 1: per-lane partial row sums of exp --------
  for (int kt = 0; kt < NWrd; ++kt) {
    const int k0 = kt * 64;
    __syncthreads();
    for (int it = 0; it < 4; ++it) {
      int idx = tid + it * 256;
      int r = idx >> 4, c8 = (idx & 15) << 3;
      *(halfx8*)&Ks[r * 136 + c8] = *(const halfx8*)(Kg + (size_t)(k0 + r) * Dd + c8);
    }
    u64 mw[4];
#pragma unroll
    for (int r = 0; r < 4; ++r) mw[r] = Mg[(size_t)(lrow + r) * NWrd + kt];
    __syncthreads();
#pragma unroll
    for (int nt = 0; nt < 4; ++nt) {
      floatx4 acc = {0.f, 0.f, 0.f, 0.f};
#pragma unroll
      for (int ks = 0; ks < 4; ++ks) {
        halfx8 bf = *(const halfx8*)&Ks[(nt * 16 + l16) * 136 + ks * 32 + quad * 8];
        acc = __builtin_amdgcn_mfma_f32_16x16x32_f16(qa[ks], bf, acc, 0, 0, 0);
      }
      const int sh = nt * 16 + l16;
#pragma unroll
      for (int r = 0; r < 4; ++r) {
        float e = ((mw[r] >> sh) & 1) ? __expf(acc[r]) : 0.0f;
        lacc[r] += e;  // reduce across l16 AFTER the loop
      }
    }
  }
  float inv[4];
#pragma unroll
  for (int r = 0; r < 4; ++r) {
    float s = lacc[r];
    s += __shfl_xor(s, 1);
    s += __shfl_xor(s, 2);
    s += __shfl_xor(s, 4);
    s += __shfl_xor(s, 8);
    inv[r] = 1.0f / s;
  }

  floatx4 cacc[8];
#pragma unroll
  for (int i = 0; i < 8; ++i) cacc[i] = (floatx4){0.f, 0.f, 0.f, 0.f};
  float* attn_base = attn_out + (size_t)bh * Ss * Ss;

  // -------- pass 2: normalized attention out + fused PV --------
  for (int kt = 0; kt < NWrd; ++kt) {
    const int k0 = kt * 64;
    __syncthreads();
    for (int it = 0; it < 4; ++it) {
      int idx = tid + it * 256;
      int r = idx >> 4, c8 = (idx & 15) << 3;
      *(halfx8*)&Ks[r * 136 + c8] = *(const halfx8*)(Kg + (size_t)(k0 + r) * Dd + c8);
    }
    for (int it = 0; it < 4; ++it) {
      int idx = tid + it * 256;
      int r = idx >> 3, c8 = (idx & 7) << 3;
      *(halfx8*)&Vts[r * 72 + c8] = *(const halfx8*)(Vtg + (size_t)r * Ss + k0 + c8);
    }
    u64 mw[4];
#pragma unroll
    for (int r = 0; r < 4; ++r) mw[r] = Mg[(size_t)(lrow + r) * NWrd + kt];
    __syncthreads();
#pragma unroll
    for (int nt = 0; nt < 4; ++nt) {
      floatx4 acc = {0.f, 0.f, 0.f, 0.f};
#pragma unroll
      for (int ks = 0; ks < 4; ++ks) {
        halfx8 bf = *(const halfx8*)&Ks[(nt * 16 + l16) * 136 + ks * 32 + quad * 8];
        acc = __builtin_amdgcn_mfma_f32_16x16x32_f16(qa[ks], bf, acc, 0, 0, 0);
      }
      const int sh = nt * 16 + l16;
#pragma unroll
      for (int r = 0; r < 4; ++r) {
        float p = ((mw[r] >> sh) & 1) ? __expf(acc[r]) * inv[r] : 0.0f;
        __builtin_nontemporal_store(p, &attn_base[(size_t)(qrow + r) * Ss + k0 + sh]);
        Ps[wave * (16 * 72) + (quad * 4 + r) * 72 + sh] = (half_t)p;
      }
    }
    halfx8 pa[2];
    pa[0] = *(const halfx8*)&Ps[wave * (16 * 72) + l16 * 72 + quad * 8];
    pa[1] = *(const halfx8*)&Ps[wave * (16 * 72) + l16 * 72 + 32 + quad * 8];
#pragma unroll
    for (int nt2 = 0; nt2 < 8; ++nt2) {
#pragma unroll
      for (int ks = 0; ks < 2; ++ks) {
        halfx8 bv = *(const halfx8*)&Vts[(nt2 * 16 + l16) * 72 + ks * 32 + quad * 8];
        cacc[nt2] = __builtin_amdgcn_mfma_f32_16x16x32_f16(pa[ks], bv, cacc[nt2], 0, 0, 0);
      }
    }
  }

  float* ctx = ctx_out + (size_t)bh * Ss * Dd;
#pragma unroll
  for (int nt2 = 0; nt2 < 8; ++nt2) {
#pragma unroll
    for (int r = 0; r < 4; ++r) {
      ctx[(size_t)(qrow + r) * Dd + nt2 * 16 + l16] = cacc[nt2][r];
    }
  }
}

extern "C" void kernel_launch(void* const* d_in, const int* in_sizes, int n_in,
                              void* d_out, int out_size, void* d_ws, size_t ws_size,
                              hipStream_t stream) {
  const float* Q = (const float*)d_in[0];
  const float* K = (const float*)d_in[1];
  const float* V = (const float*)d_in[2];
  const int* mask = (const int*)d_in[3];
  const float* scale = (const float*)d_in[4];
  float* ctx = (float*)d_out;
  float* attn = (float*)d_out + (size_t)Bb * Hh * Ss * Dd;

  const size_t nqk = (size_t)Bb * Hh * Ss * Dd;  // 8388608
  half_t* Qh = (half_t*)d_ws;
  half_t* Kh = Qh + nqk;
  half_t* Vt = Kh + nqk;
  u64* Mbits = (u64*)(Vt + nqk);  // 1 MB

  cvt_qk_kernel<<<nqk / (256 * 8), 256, 0, stream>>>(Q, K, scale, Qh, Kh);
  dim3 gt(Ss / 64, Dd / 64, Bb * Hh);
  vt_kernel<<<gt, 256, 0, stream>>>(V, Vt);
  mask_pack_kernel<<<((size_t)Bb * Ss * NWrd) / 4, 256, 0, stream>>>(mask, Mbits);
  dim3 gm(Ss / 64, Hh, Bb);
  attn_kernel<<<gm, 256, 0, stream>>>(Qh, Kh, Mbits, Vt, ctx, attn);
}